// Round 9
// baseline (760.974 us; speedup 1.0000x reference)
//
#include <hip/hip_runtime.h>
#include <hip/hip_bf16.h>
#include <cstdint>

#define DEVINL __device__ __forceinline__

namespace {
constexpr int B = 4, T = 256, U = 101, V = 1024;
constexpr int BLANK = 1023;
constexpr float SIGMA = 0.05f;
constexpr int TU = T * U;
constexpr int BTU = B * TU;
constexpr int ROWLEN = V + 5;    // 1029
constexpr int KP = 376;          // padded diag rows (max touched row = 368)
constexpr int UP = 128;          // padded u stride (A plane)
constexpr int CELLS = B * KP * UP;
constexpr int A_FLOATS = CELLS * 4;   // 8 bf16 (16B) per cell
constexpr int M4_FLOATS = CELLS / 2;  // uint32 (2 bf16) per (row, lane)
constexpr int NCONS = 4;              // consumer blocks (one per batch)
constexpr int NCHUNK = 32;            // t-chunks per batch (8 t-values each)
constexpr int RPC = 8 * U;            // rows per chunk = 808
constexpr float LN2 = 0.6931471805599453f;
}

DEVINL float lo16(uint32_t v) { return __uint_as_float(v << 16); }
DEVINL float hi16(uint32_t v) { return __uint_as_float(v & 0xffff0000u); }
DEVINL float mkscale(int d) {
  return ((unsigned)(d + 126) <= 252u) ? ldexpf(1.0f, d) : 0.0f;
}
DEVINL unsigned short f2bf(float x) {
  __hip_bfloat16 h = __float2bfloat16(x);
  unsigned short v;
  __builtin_memcpy(&v, &h, 2);
  return v;
}
// agent-scope coherent 2B store (reaches device coherence point, no fence needed)
DEVINL void ast(unsigned short* p, unsigned short v) {
  __hip_atomic_store(p, v, __ATOMIC_RELAXED, __HIP_MEMORY_SCOPE_AGENT);
}

// ---------------- K0: zero-fill weight planes + counters ----------------
__global__ void __launch_bounds__(256) k_fill(float4* __restrict__ w, int n4) {
  int i = blockIdx.x * 256 + threadIdx.x;
  if (i < n4) w[i] = float4{0.f, 0.f, 0.f, 0.f};
}

// ---------------- fused producer/consumer ----------------
struct OpsP { int4 a0, a1; uint32_t m4; };

DEVINL OpsP load_ops(const int4* __restrict__ pA, const uint32_t* __restrict__ pM4,
                     int row, int l) {
  OpsP o;
  int i0 = row * UP + l;
  o.a0 = pA[i0];
  o.a1 = pA[i0 + 64];
  o.m4 = pM4[row * 64 + l];
  return o;
}

__global__ void __launch_bounds__(256) k_fused(
    const float* __restrict__ acts, const int* __restrict__ labels,
    const int* __restrict__ act_lens, const int* __restrict__ label_lens,
    unsigned short* __restrict__ A, unsigned short* __restrict__ M4p,
    int* __restrict__ cnt, float* __restrict__ partial) {
  if (blockIdx.x >= NCONS) {
    // ================= producer: one wave per (b,t,u) row =================
    const int gwave = (blockIdx.x - NCONS) * 4 + (threadIdx.x >> 6);
    const int lane = threadIdx.x & 63;
    const int b = gwave / TU;
    const int rem = gwave - b * TU;
    const int t = rem / U;
    const int u = rem - t * U;
    const float* row = acts + (size_t)gwave * ROWLEN;

    float x[16];
#pragma unroll
    for (int j = 0; j < 16; ++j) x[j] = row[j * 64 + lane];
    float m = x[0];
#pragma unroll
    for (int j = 1; j < 16; ++j) m = fmaxf(m, x[j]);
#pragma unroll
    for (int off = 32; off >= 1; off >>= 1) m = fmaxf(m, __shfl_xor(m, off, 64));
    float s = 0.f;
#pragma unroll
    for (int j = 0; j < 16; ++j) s += __expf(x[j] - m);
#pragma unroll
    for (int off = 32; off >= 1; off >>= 1) s += __shfl_xor(s, off, 64);

    if (lane == 0) {
      float inv_s = 1.0f / s;
      float pb = __expf(row[BLANK] - m - SIGMA) * inv_s;   // exp(blank_lp)
      int lab = (u < U - 1) ? labels[b * (U - 1) + u] : 0;
      float py = __expf(row[lab] - m - SIGMA) * inv_s;     // exp(y_lp)
      float d0 = row[V], d1 = row[V + 1], d2 = row[V + 2], d3 = row[V + 3], d4 = row[V + 4];
      float dm = fmaxf(fmaxf(fmaxf(d0, d1), fmaxf(d2, d3)), d4);
      float e0x = __expf(d0 - dm), e1x = __expf(d1 - dm), e2x = __expf(d2 - dm),
            e3x = __expf(d3 - dm), e4x = __expf(d4 - dm);
      float invd = 1.0f / (e0x + e1x + e2x + e3x + e4x);
      float q0 = e0x * invd, q1 = e1x * invd, q2 = e2x * invd,
            q3 = e3x * invd, q4 = e4x * invd;

      int col = ((u & 1) << 6) | (u >> 1);
      int base = b * KP + t + u;
      int c1 = ((base + 1) * UP + col) * 8;
      int c2 = ((base + 2) * UP + col) * 8;
      int c3 = ((base + 3) * UP + col) * 8;
      int c4 = ((base + 4) * UP + col) * 8;
      ast(&A[c1 + 0], f2bf(pb * q1));
      ast(&A[c2 + 1], f2bf(pb * q2));
      ast(&A[c3 + 2], f2bf(pb * q3));
      ast(&A[c4 + 3], f2bf(pb * q4));
      if (u + 1 < U) {
        ast(&A[c1 + 4], f2bf(py * q0));   // E
        ast(&A[c2 + 5], f2bf(py * q1));   // M1
        ast(&A[c3 + 6], f2bf(py * q2));   // M2
        ast(&A[c4 + 7], f2bf(py * q3));   // M3
        ast(&M4p[((base + 5) * 64 + (u >> 1)) * 2 + (u & 1)], f2bf(py * q4));
      }
      asm volatile("s_waitcnt vmcnt(0)" ::: "memory");  // stores at coherence point
      __hip_atomic_fetch_add(&cnt[b * NCHUNK + (t >> 3)], 1,
                             __ATOMIC_RELAXED, __HIP_MEMORY_SCOPE_AGENT);
    }
    return;
  }

  // ================= consumer: diagonal DP, one wave per batch =================
  if (threadIdx.x >= 64) return;
  const int b = blockIdx.x;
  const int l = threadIdx.x;
  const int al = act_lens[b];
  const int ll = label_lens[b];
  const int4* pA = reinterpret_cast<const int4*>(A) + b * KP * UP;
  const uint32_t* pM4 = reinterpret_cast<const uint32_t*>(M4p) + b * KP * 64;
  int* pcnt = cnt + b * NCHUNK;

  const int u0 = 2 * l, u1 = 2 * l + 1;
  const bool isLL0 = (u0 == ll), isLL1 = (u1 == ll);
  const int kbase = al + ll - 4;

  float h0[5] = {0, 0, 0, 0, 0}, h1[5] = {0, 0, 0, 0, 0};
  int o0 = 0, o1 = 0;
  if (l == 0) h0[0] = 1.0f;   // alpha(0,0) = 1 (diag 0); loop starts at k=1
  float cm0 = 0, cm1 = 0, cm2 = 0, cm3 = 0;
  int co0 = -100000, co1 = -100000, co2 = -100000, co3 = -100000;

  int doneChunk = 0;  // chunks [0, doneChunk) complete
  auto waitChunks = [&](int cs) {
    while (doneChunk <= cs) {
      int v = __hip_atomic_load(pcnt + doneChunk, __ATOMIC_RELAXED,
                                __HIP_MEMORY_SCOPE_AGENT);
      if (v >= RPC) {
        __builtin_amdgcn_fence(__ATOMIC_ACQUIRE, "agent");  // inv stale clean lines
        ++doneChunk;
      } else {
        __builtin_amdgcn_s_sleep(2);
      }
    }
  };

  waitChunks(0);                 // rows 1..8 (t <= 7)
  OpsP q[8];
#pragma unroll
  for (int j = 0; j < 8; ++j) q[j] = load_ops(pA, pM4, j + 1, l);

  for (int blk = 0; blk < 45; ++blk) {
    const int kblk = blk * 8 + 1;
#pragma unroll
    for (int w = 0; w < 2; ++w) {
      {  // gate this window's prefetches (rows up to k_last+8)
        int sN = kblk + w * 4 + 3 + 7;
        int tmx = (sN < T) ? sN : (T - 1);
        waitChunks(tmx >> 3);
      }
      // ---- window start: renorm both slots, adopt dead offsets, scales ----
      float pv0 = fmaxf(fmaxf(fmaxf(h0[0], h0[1]), fmaxf(h0[2], h0[3])), h0[4]);
      int eb0 = (int)((__float_as_uint(pv0) >> 23) & 0xffu);
      bool dead0 = (eb0 == 0);
      int d0 = dead0 ? 0 : (127 - eb0);
#pragma unroll
      for (int i = 0; i < 5; ++i) h0[i] = ldexpf(h0[i], d0);
      o0 -= d0;
      float pv1 = fmaxf(fmaxf(fmaxf(h1[0], h1[1]), fmaxf(h1[2], h1[3])), h1[4]);
      int eb1 = (int)((__float_as_uint(pv1) >> 23) & 0xffu);
      bool dead1 = (eb1 == 0);
      int d1 = dead1 ? 0 : (127 - eb1);
#pragma unroll
      for (int i = 0; i < 5; ++i) h1[i] = ldexpf(h1[i], d1);
      o1 -= d1;
#pragma unroll
      for (int r = 0; r < 3; ++r) {
        int on = __shfl_up(o1, 1, 64);
        if (dead0 && l > 0) o0 = on;
        if (dead1) o1 = o0;
      }
      int on0 = __shfl_up(o1, 1, 64);
      float scN = (l == 0) ? 0.0f : mkscale(on0 - o0);  // help1(l-1) -> slot0
      float sc10 = mkscale(o0 - o1);                    // help0 -> slot1 (same lane)

      // ---- 4 diagonals, offsets frozen ----
#pragma unroll
      for (int j = 0; j < 4; ++j) {
        const int rj = w * 4 + j;
        const int k = kblk + rj;
        OpsP cur = q[rj];
        q[rj] = load_ops(pA, pM4, k + 8, l);   // row <= 368 < KP

        uint32_t a0x = (uint32_t)cur.a0.x, a0y = (uint32_t)cur.a0.y;
        uint32_t a0z = (uint32_t)cur.a0.z, a0w = (uint32_t)cur.a0.w;
        uint32_t a1x = (uint32_t)cur.a1.x, a1y = (uint32_t)cur.a1.y;
        uint32_t a1z = (uint32_t)cur.a1.z, a1w = (uint32_t)cur.a1.w;

        float self0 = fmaf(h0[0], lo16(a0x), fmaf(h0[1], hi16(a0x),
                       fmaf(h0[2], lo16(a0y), h0[3] * hi16(a0y))));
        float help0 = fmaf(h0[0], lo16(a0z), fmaf(h0[1], hi16(a0z),
                       fmaf(h0[2], lo16(a0w), fmaf(h0[3], hi16(a0w),
                        h0[4] * lo16(cur.m4)))));
        float self1 = fmaf(h1[0], lo16(a1x), fmaf(h1[1], hi16(a1x),
                       fmaf(h1[2], lo16(a1y), h1[3] * hi16(a1y))));
        float help1 = fmaf(h1[0], lo16(a1z), fmaf(h1[1], hi16(a1z),
                       fmaf(h1[2], lo16(a1w), fmaf(h1[3], hi16(a1w),
                        h1[4] * hi16(cur.m4)))));

        float n0 = __shfl_up(help1, 1, 64);     // mass into u0 from lane l-1
        float r0 = fmaf(n0, scN, self0);
        float r1 = fmaf(help0, sc10, self1);

        float r0g = ((unsigned)(k - u0) < (unsigned)T) ? r0 : 0.0f;
        float r1g = ((unsigned)(k - u1) < (unsigned)T) ? r1 : 0.0f;

        // capture alpha(al-d,ll) mantissa/offset at k = al-d+ll (sg applied at end)
        unsigned idx = (unsigned)(k - kbase);
        if (idx < 4u && (isLL0 | isLL1)) {
          float tm = isLL0 ? r0g : r1g;
          int to = isLL0 ? o0 : o1;
          if (idx == 0) { cm0 = tm; co0 = to; }
          else if (idx == 1) { cm1 = tm; co1 = to; }
          else if (idx == 2) { cm2 = tm; co2 = to; }
          else { cm3 = tm; co3 = to; }
        }

        h0[4] = h0[3]; h0[3] = h0[2]; h0[2] = h0[1]; h0[1] = h0[0]; h0[0] = r0g;
        h1[4] = h1[3]; h1[3] = h1[2]; h1[2] = h1[1]; h1[1] = h1[0]; h1[0] = r1g;
      }
    }
  }

  waitChunks(NCHUNK - 1);   // full batch (also covers sgf row)
  if (isLL0 | isLL1) {
    const int cll = ((ll & 1) << 6) | (ll >> 1);
    const int4 av = pA[(al + ll) * UP + cll];
    float sg1 = lo16((uint32_t)av.x), sg2 = hi16((uint32_t)av.x);
    float sg3 = lo16((uint32_t)av.y), sg4 = hi16((uint32_t)av.y);
    int mo = co0 > co1 ? co0 : co1;
    mo = mo > co2 ? mo : co2;
    mo = mo > co3 ? mo : co3;
    float sum = ldexpf(cm0 * sg4, co0 - mo) + ldexpf(cm1 * sg3, co1 - mo) +
                ldexpf(cm2 * sg2, co2 - mo) + ldexpf(cm3 * sg1, co3 - mo);
    partial[b] = -(log2f(sum) + (float)mo) * LN2;
  }
}

// ---------------- K3: batch reduce ----------------
__global__ void k_final(const float* __restrict__ partial, float* __restrict__ out) {
  if (threadIdx.x == 0 && blockIdx.x == 0)
    out[0] = (partial[0] + partial[1] + partial[2] + partial[3]) * 0.25f;
}

extern "C" void kernel_launch(void* const* d_in, const int* in_sizes, int n_in,
                              void* d_out, int out_size, void* d_ws, size_t ws_size,
                              hipStream_t stream) {
  const float* acts = (const float*)d_in[0];
  const int* labels = (const int*)d_in[1];
  const int* act_lens = (const int*)d_in[2];
  const int* label_lens = (const int*)d_in[3];
  float* ws = (float*)d_ws;
  unsigned short* A = (unsigned short*)ws;                      // CELLS x 8 bf16
  unsigned short* M4p = (unsigned short*)(ws + A_FLOATS);       // CELLS/2 x uint32
  float* partial = ws + A_FLOATS + M4_FLOATS;                   // [B]
  int* cnt = (int*)(partial + B);                               // [B][NCHUNK]
  float* out = (float*)d_out;

  int n4 = (A_FLOATS + M4_FLOATS + B + B * NCHUNK) / 4;
  k_fill<<<(n4 + 255) / 256, 256, 0, stream>>>(reinterpret_cast<float4*>(ws), n4);
  k_fused<<<NCONS + BTU / 4, 256, 0, stream>>>(acts, labels, act_lens, label_lens,
                                               A, M4p, cnt, partial);
  k_final<<<1, 64, 0, stream>>>(partial, out);
}

// Round 10
// 165.918 us; speedup vs baseline: 4.5864x; 4.5864x over previous
//
#include <hip/hip_runtime.h>
#include <hip/hip_bf16.h>
#include <cstdint>

#define DEVINL __device__ __forceinline__

namespace {
constexpr int B = 4, T = 256, U = 101, V = 1024;
constexpr int BLANK = 1023;
constexpr float SIGMA = 0.05f;
constexpr int TU = T * U;
constexpr int BTU = B * TU;
constexpr int ROWLEN = V + 5;    // 1029
constexpr int KP = 376;          // padded diag rows (max touched row = 372)
constexpr int UP = 128;          // padded u stride (A plane)
constexpr int CELLS = B * KP * UP;
constexpr int A_FLOATS = CELLS * 4;   // int4 (8 bf16) per cell
constexpr int M4_FLOATS = CELLS / 2;  // uint32 (2 bf16) per (row, lane)
constexpr float LN2 = 0.6931471805599453f;
}

DEVINL float lo16(uint32_t v) { return __uint_as_float(v << 16); }
DEVINL float hi16(uint32_t v) { return __uint_as_float(v & 0xffff0000u); }
// 2^d as float; out-of-range -> 0 (drops negligible/dead-edge mass only)
DEVINL float mkscale(int d) {
  return ((unsigned)(d + 126) <= 252u) ? ldexpf(1.0f, d) : 0.0f;
}

// ---------------- K0: zero-fill weight planes ----------------
__global__ void __launch_bounds__(256) k_fill(float4* __restrict__ w, int n4) {
  int i = blockIdx.x * 256 + threadIdx.x;
  if (i < n4) w[i] = float4{0.f, 0.f, 0.f, 0.f};
}

// ---------------- K1: ALIGNED softmax rows -> bf16 diagonal weight planes ----
// One wave per row. Row r starts at float r*1029 with phase p = r mod 4; the
// wave loads the 16B-aligned float4 window [start-p, start-p+1024) with 4
// coalesced loads + 1 lane-0 corrective float4. The p leading pre-row elems
// are masked to -inf (excluded from max & sum); the p trailing label elems
// (c in [1024-p,1024)) come from the corrective load. Windows of consecutive
// rows tile memory -> no HBM over-fetch.
__global__ void __launch_bounds__(256) k_prep(
    const float* __restrict__ acts, const int* __restrict__ labels,
    __hip_bfloat16* __restrict__ A, __hip_bfloat16* __restrict__ M4p) {
  int gwave = (blockIdx.x * 256 + threadIdx.x) >> 6;
  int lane = threadIdx.x & 63;
  if (gwave >= BTU) return;
  int b = gwave / TU;
  int rem = gwave - b * TU;
  int t = rem / U;
  int u = rem - t * U;
  const size_t start = (size_t)gwave * ROWLEN;
  const int p = gwave & 3;   // start % 4 (1029 ≡ 1 mod 4)
  const float4* w4 = reinterpret_cast<const float4*>(acts + (start - p));

  float4 xa = w4[lane];
  float4 xb = w4[64 + lane];
  float4 xc = w4[128 + lane];
  float4 xd = w4[192 + lane];
  float ex0 = -INFINITY, ex1 = -INFINITY, ex2 = -INFINITY;
  if (p && lane == 0) {
    float4 e = w4[256];                    // floats c = 1024-p .. 1027-p
    ex0 = e.x;
    ex1 = (p > 1) ? e.y : -INFINITY;
    ex2 = (p > 2) ? e.z : -INFINITY;
    // mask the p pre-row elements out of this lane's first float4
    xa.x = -INFINITY;
    if (p > 1) xa.y = -INFINITY;
    if (p > 2) xa.z = -INFINITY;
  }

  float m = fmaxf(fmaxf(fmaxf(xa.x, xa.y), fmaxf(xa.z, xa.w)),
                  fmaxf(fmaxf(xb.x, xb.y), fmaxf(xb.z, xb.w)));
  m = fmaxf(m, fmaxf(fmaxf(xc.x, xc.y), fmaxf(xc.z, xc.w)));
  m = fmaxf(m, fmaxf(fmaxf(xd.x, xd.y), fmaxf(xd.z, xd.w)));
  m = fmaxf(m, fmaxf(fmaxf(ex0, ex1), ex2));
#pragma unroll
  for (int off = 32; off >= 1; off >>= 1) m = fmaxf(m, __shfl_xor(m, off, 64));

  float s = __expf(xa.x - m) + __expf(xa.y - m) + __expf(xa.z - m) + __expf(xa.w - m) +
            __expf(xb.x - m) + __expf(xb.y - m) + __expf(xb.z - m) + __expf(xb.w - m) +
            __expf(xc.x - m) + __expf(xc.y - m) + __expf(xc.z - m) + __expf(xc.w - m) +
            __expf(xd.x - m) + __expf(xd.y - m) + __expf(xd.z - m) + __expf(xd.w - m);
  if (p && lane == 0)
    s += __expf(ex0 - m) + __expf(ex1 - m) + __expf(ex2 - m);
#pragma unroll
  for (int off = 32; off >= 1; off >>= 1) s += __shfl_xor(s, off, 64);

  if (lane == 0) {
    const float* row = acts + start;
    float inv_s = 1.0f / s;
    float pb = __expf(row[BLANK] - m - SIGMA) * inv_s;   // exp(blank_lp)
    int lab = (u < U - 1) ? labels[b * (U - 1) + u] : 0;
    float py = __expf(row[lab] - m - SIGMA) * inv_s;     // exp(y_lp)
    float d0 = row[V], d1 = row[V + 1], d2 = row[V + 2], d3 = row[V + 3], d4 = row[V + 4];
    float dm = fmaxf(fmaxf(fmaxf(d0, d1), fmaxf(d2, d3)), d4);
    float e0x = __expf(d0 - dm), e1x = __expf(d1 - dm), e2x = __expf(d2 - dm),
          e3x = __expf(d3 - dm), e4x = __expf(d4 - dm);
    float invd = 1.0f / (e0x + e1x + e2x + e3x + e4x);
    float q0 = e0x * invd, q1 = e1x * invd, q2 = e2x * invd,
          q3 = e3x * invd, q4 = e4x * invd;

    int col = ((u & 1) << 6) | (u >> 1);
    int base = b * KP + t + u;
    int c1 = ((base + 1) * UP + col) * 8;
    int c2 = ((base + 2) * UP + col) * 8;
    int c3 = ((base + 3) * UP + col) * 8;
    int c4 = ((base + 4) * UP + col) * 8;
    A[c1 + 0] = __float2bfloat16(pb * q1);
    A[c2 + 1] = __float2bfloat16(pb * q2);
    A[c3 + 2] = __float2bfloat16(pb * q3);
    A[c4 + 3] = __float2bfloat16(pb * q4);
    if (u + 1 < U) {
      A[c1 + 4] = __float2bfloat16(py * q0);   // E
      A[c2 + 5] = __float2bfloat16(py * q1);   // M1
      A[c3 + 6] = __float2bfloat16(py * q2);   // M2
      A[c4 + 7] = __float2bfloat16(py * q3);   // M3
      M4p[((base + 5) * 64 + (u >> 1)) * 2 + (u & 1)] = __float2bfloat16(py * q4);
    }
  }
}

// ---------------- K2: linear-domain diagonal DP, windowed renorm ----------------
struct OpsP { int4 a0, a1; uint32_t m4; };

DEVINL OpsP load_ops(const int4* __restrict__ pA, const uint32_t* __restrict__ pM4,
                     int row, int l) {
  OpsP o;
  int i0 = row * UP + l;
  o.a0 = pA[i0];
  o.a1 = pA[i0 + 64];
  o.m4 = pM4[row * 64 + l];
  return o;
}

__global__ void __launch_bounds__(64, 1) k_dp(
    const int4* __restrict__ PA, const uint32_t* __restrict__ PM4,
    const int* __restrict__ act_lens, const int* __restrict__ label_lens,
    float* __restrict__ partial) {
  const int b = blockIdx.x;
  const int l = threadIdx.x;
  const int al = act_lens[b];
  const int ll = label_lens[b];
  const int4* pA = PA + b * KP * UP;
  const uint32_t* pM4 = PM4 + b * KP * 64;

  const int cll = ((ll & 1) << 6) | (ll >> 1);
  const int4 av = pA[(al + ll) * UP + cll];
  const float sg1 = lo16((uint32_t)av.x), sg2 = hi16((uint32_t)av.x);
  const float sg3 = lo16((uint32_t)av.y), sg4 = hi16((uint32_t)av.y);
  const int u0 = 2 * l, u1 = 2 * l + 1;
  const bool isLL0 = (u0 == ll), isLL1 = (u1 == ll);
  const int kbase = al + ll - 4;

  // history: h[0] = alpha(diag k-1), ..., h[4] = alpha(diag k-5); offsets o0/o1
  float h0[5] = {0, 0, 0, 0, 0}, h1[5] = {0, 0, 0, 0, 0};
  int o0 = 0, o1 = 0;
  if (l == 0) h0[0] = 1.0f;   // alpha(0,0) = 1 (diag 0); loop starts at k=1
  float tAm = 0.0f; int tAo = -100000;

  OpsP q[12];
#pragma unroll
  for (int j = 0; j < 12; ++j) q[j] = load_ops(pA, pM4, j + 1, l);

  for (int blk = 0; blk < 30; ++blk) {
    const int kblk = blk * 12 + 1;
#pragma unroll
    for (int w = 0; w < 3; ++w) {
      // ---- window start: renorm both slots, adopt dead offsets, scales ----
      float pv0 = fmaxf(fmaxf(fmaxf(h0[0], h0[1]), fmaxf(h0[2], h0[3])), h0[4]);
      int eb0 = (int)((__float_as_uint(pv0) >> 23) & 0xffu);
      bool dead0 = (eb0 == 0);
      int d0 = dead0 ? 0 : (127 - eb0);
#pragma unroll
      for (int i = 0; i < 5; ++i) h0[i] = ldexpf(h0[i], d0);
      o0 -= d0;
      float pv1 = fmaxf(fmaxf(fmaxf(h1[0], h1[1]), fmaxf(h1[2], h1[3])), h1[4]);
      int eb1 = (int)((__float_as_uint(pv1) >> 23) & 0xffu);
      bool dead1 = (eb1 == 0);
      int d1 = dead1 ? 0 : (127 - eb1);
#pragma unroll
      for (int i = 0; i < 5; ++i) h1[i] = ldexpf(h1[i], d1);
      o1 -= d1;
      // offset adoption for dead slots (3 rounds: outruns the diagonal front)
#pragma unroll
      for (int r = 0; r < 3; ++r) {
        int on = __shfl_up(o1, 1, 64);
        if (dead0 && l > 0) o0 = on;
        if (dead1) o1 = o0;
      }
      int on0 = __shfl_up(o1, 1, 64);
      float scN = (l == 0) ? 0.0f : mkscale(on0 - o0);  // help1(l-1) -> slot0
      float sc10 = mkscale(o0 - o1);                    // help0 -> slot1 (same lane)

      // ---- 4 diagonals, offsets frozen ----
#pragma unroll
      for (int j = 0; j < 4; ++j) {
        const int rj = w * 4 + j;
        const int k = kblk + rj;
        OpsP cur = q[rj];
        q[rj] = load_ops(pA, pM4, k + 12, l);   // row <= 372 < KP

        uint32_t a0x = (uint32_t)cur.a0.x, a0y = (uint32_t)cur.a0.y;
        uint32_t a0z = (uint32_t)cur.a0.z, a0w = (uint32_t)cur.a0.w;
        uint32_t a1x = (uint32_t)cur.a1.x, a1y = (uint32_t)cur.a1.y;
        uint32_t a1z = (uint32_t)cur.a1.z, a1w = (uint32_t)cur.a1.w;

        float self0 = fmaf(h0[0], lo16(a0x), fmaf(h0[1], hi16(a0x),
                       fmaf(h0[2], lo16(a0y), h0[3] * hi16(a0y))));
        float help0 = fmaf(h0[0], lo16(a0z), fmaf(h0[1], hi16(a0z),
                       fmaf(h0[2], lo16(a0w), fmaf(h0[3], hi16(a0w),
                        h0[4] * lo16(cur.m4)))));
        float self1 = fmaf(h1[0], lo16(a1x), fmaf(h1[1], hi16(a1x),
                       fmaf(h1[2], lo16(a1y), h1[3] * hi16(a1y))));
        float help1 = fmaf(h1[0], lo16(a1z), fmaf(h1[1], hi16(a1z),
                       fmaf(h1[2], lo16(a1w), fmaf(h1[3], hi16(a1w),
                        h1[4] * hi16(cur.m4)))));

        float n0 = __shfl_up(help1, 1, 64);     // mass into u0 from lane l-1
        float r0 = fmaf(n0, scN, self0);
        float r1 = fmaf(help0, sc10, self1);

        float r0g = ((unsigned)(k - u0) < (unsigned)T) ? r0 : 0.0f;
        float r1g = ((unsigned)(k - u1) < (unsigned)T) ? r1 : 0.0f;

        // final-term capture: alpha(al-d,ll) * S_d(al-d,ll) at k = al-d+ll
        unsigned idx = (unsigned)(k - kbase);
        if (idx < 4u) {
          if (isLL0 | isLL1) {
            float sg = (idx == 0) ? sg4 : (idx == 1) ? sg3 : (idx == 2) ? sg2 : sg1;
            float tm = (isLL0 ? r0g : r1g) * sg;
            int to = isLL0 ? o0 : o1;
            int nb2 = (tAo > to) ? tAo : to;
            tAm = ldexpf(tAm, tAo - nb2) + ldexpf(tm, to - nb2);
            tAo = nb2;
          }
        }

        // history shift: pure register renaming (offsets frozen in window)
        h0[4] = h0[3]; h0[3] = h0[2]; h0[2] = h0[1]; h0[1] = h0[0]; h0[0] = r0g;
        h1[4] = h1[3]; h1[3] = h1[2]; h1[2] = h1[1]; h1[1] = h1[0]; h1[0] = r1g;
      }
    }
  }

  if (isLL0 | isLL1) partial[b] = -(log2f(tAm) + (float)tAo) * LN2;
}

// ---------------- K3: batch reduce ----------------
__global__ void k_final(const float* __restrict__ partial, float* __restrict__ out) {
  if (threadIdx.x == 0 && blockIdx.x == 0)
    out[0] = (partial[0] + partial[1] + partial[2] + partial[3]) * 0.25f;
}

extern "C" void kernel_launch(void* const* d_in, const int* in_sizes, int n_in,
                              void* d_out, int out_size, void* d_ws, size_t ws_size,
                              hipStream_t stream) {
  const float* acts = (const float*)d_in[0];
  const int* labels = (const int*)d_in[1];
  const int* act_lens = (const int*)d_in[2];
  const int* label_lens = (const int*)d_in[3];
  float* ws = (float*)d_ws;
  __hip_bfloat16* A = (__hip_bfloat16*)ws;                 // CELLS x 8 bf16
  __hip_bfloat16* M4p = (__hip_bfloat16*)(ws + A_FLOATS);  // CELLS/2 x uint32
  float* partial = ws + A_FLOATS + M4_FLOATS;              // [B]
  float* out = (float*)d_out;

  int n4 = (A_FLOATS + M4_FLOATS) / 4;
  k_fill<<<(n4 + 255) / 256, 256, 0, stream>>>(reinterpret_cast<float4*>(ws), n4);
  k_prep<<<BTU / 4, 256, 0, stream>>>(acts, labels, A, M4p);
  k_dp<<<B, 64, 0, stream>>>(reinterpret_cast<const int4*>(A),
                             reinterpret_cast<const uint32_t*>(M4p),
                             act_lens, label_lens, partial);
  k_final<<<1, 64, 0, stream>>>(partial, out);
}

// Round 11
// 155.592 us; speedup vs baseline: 4.8908x; 1.0664x over previous
//
#include <hip/hip_runtime.h>
#include <hip/hip_bf16.h>
#include <cstdint>

#define DEVINL __device__ __forceinline__

namespace {
constexpr int B = 4, T = 256, U = 101, V = 1024;
constexpr int BLANK = 1023;
constexpr float SIGMA = 0.05f;
constexpr int TU = T * U;
constexpr int BTU = B * TU;
constexpr int ROWLEN = V + 5;    // 1029
constexpr int KP = 376;          // padded diag rows (max touched row = 372)
constexpr int UP = 128;          // padded u stride (A plane)
constexpr int CELLS = B * KP * UP;
constexpr int A_FLOATS = CELLS * 4;   // int4 (8 bf16) per cell
constexpr int M4_FLOATS = CELLS / 2;  // uint32 (2 bf16) per (row, lane)
constexpr float LN2 = 0.6931471805599453f;
}

DEVINL float lo16(uint32_t v) { return __uint_as_float(v << 16); }
DEVINL float hi16(uint32_t v) { return __uint_as_float(v & 0xffff0000u); }
// 2^d as float; out-of-range -> 0 (drops negligible/dead-edge mass only)
DEVINL float mkscale(int d) {
  return ((unsigned)(d + 126) <= 252u) ? ldexpf(1.0f, d) : 0.0f;
}

// ---------------- K0: zero-fill weight planes ----------------
__global__ void __launch_bounds__(256) k_fill(float4* __restrict__ w, int n4) {
  int i = blockIdx.x * 256 + threadIdx.x;
  if (i < n4) w[i] = float4{0.f, 0.f, 0.f, 0.f};
}

// ---------------- K1: softmax rows -> bf16 diagonal weight planes (R7 form) ----
// col(u) = (u&1)*64 + (u>>1): lane l of k_dp owns u=2l (col l) and u=2l+1
// (col 64+l). A[row][col] = 8 bf16 {S1..S4, E, M1..M3}. M4 plane: uint32 per
// (row, lane) = {M4(u=2l) lo, M4(u=2l+1) hi}.
__global__ void __launch_bounds__(256) k_prep(
    const float* __restrict__ acts, const int* __restrict__ labels,
    __hip_bfloat16* __restrict__ A, __hip_bfloat16* __restrict__ M4p) {
  int gwave = (blockIdx.x * 256 + threadIdx.x) >> 6;
  int lane = threadIdx.x & 63;
  if (gwave >= BTU) return;
  int b = gwave / TU;
  int rem = gwave - b * TU;
  int t = rem / U;
  int u = rem - t * U;
  const float* row = acts + (size_t)gwave * ROWLEN;

  float x[16];
#pragma unroll
  for (int j = 0; j < 16; ++j) x[j] = row[j * 64 + lane];
  float m = x[0];
#pragma unroll
  for (int j = 1; j < 16; ++j) m = fmaxf(m, x[j]);
#pragma unroll
  for (int off = 32; off >= 1; off >>= 1) m = fmaxf(m, __shfl_xor(m, off, 64));
  float s = 0.f;
#pragma unroll
  for (int j = 0; j < 16; ++j) s += __expf(x[j] - m);
#pragma unroll
  for (int off = 32; off >= 1; off >>= 1) s += __shfl_xor(s, off, 64);

  if (lane == 0) {
    float inv_s = 1.0f / s;
    float pb = __expf(row[BLANK] - m - SIGMA) * inv_s;   // exp(blank_lp)
    int lab = (u < U - 1) ? labels[b * (U - 1) + u] : 0;
    float py = __expf(row[lab] - m - SIGMA) * inv_s;     // exp(y_lp)
    float d0 = row[V], d1 = row[V + 1], d2 = row[V + 2], d3 = row[V + 3], d4 = row[V + 4];
    float dm = fmaxf(fmaxf(fmaxf(d0, d1), fmaxf(d2, d3)), d4);
    float e0x = __expf(d0 - dm), e1x = __expf(d1 - dm), e2x = __expf(d2 - dm),
          e3x = __expf(d3 - dm), e4x = __expf(d4 - dm);
    float invd = 1.0f / (e0x + e1x + e2x + e3x + e4x);
    float q0 = e0x * invd, q1 = e1x * invd, q2 = e2x * invd,
          q3 = e3x * invd, q4 = e4x * invd;

    int col = ((u & 1) << 6) | (u >> 1);
    int base = b * KP + t + u;
    int c1 = ((base + 1) * UP + col) * 8;
    int c2 = ((base + 2) * UP + col) * 8;
    int c3 = ((base + 3) * UP + col) * 8;
    int c4 = ((base + 4) * UP + col) * 8;
    A[c1 + 0] = __float2bfloat16(pb * q1);
    A[c2 + 1] = __float2bfloat16(pb * q2);
    A[c3 + 2] = __float2bfloat16(pb * q3);
    A[c4 + 3] = __float2bfloat16(pb * q4);
    if (u + 1 < U) {
      A[c1 + 4] = __float2bfloat16(py * q0);   // E
      A[c2 + 5] = __float2bfloat16(py * q1);   // M1
      A[c3 + 6] = __float2bfloat16(py * q2);   // M2
      A[c4 + 7] = __float2bfloat16(py * q3);   // M3
      M4p[((base + 5) * 64 + (u >> 1)) * 2 + (u & 1)] = __float2bfloat16(py * q4);
    }
  }
}

// ---------------- K2: linear-domain diagonal DP + L2-warming prefetch waves ----
struct OpsP { int4 a0, a1; uint32_t m4; };

DEVINL OpsP load_ops(const int4* __restrict__ pA, const uint32_t* __restrict__ pM4,
                     int row, int l) {
  OpsP o;
  int i0 = row * UP + l;
  o.a0 = pA[i0];
  o.a1 = pA[i0 + 64];
  o.m4 = pM4[row * 64 + l];
  return o;
}

__global__ void __launch_bounds__(192, 1) k_dp(
    const int4* __restrict__ PA, const uint32_t* __restrict__ PM4,
    const int* __restrict__ act_lens, const int* __restrict__ label_lens,
    float* __restrict__ partial) {
  const int b = blockIdx.x;
  const int4* pA = PA + b * KP * UP;
  const uint32_t* pM4 = PM4 + b * KP * 64;

  if (threadIdx.x >= 64) {
    // ---- prefetcher waves: sweep the batch's plane into the local XCD L2 ----
    const int pw = (threadIdx.x >> 6) - 1;   // 0 or 1
    const int l = threadIdx.x & 63;
    int acc = 0;
#pragma unroll 4
    for (int row = 1 + pw; row <= 372; row += 2) {
      int i0 = row * UP + l;
      int4 a = pA[i0];
      int4 c = pA[i0 + 64];
      uint32_t m = pM4[row * 64 + l];
      acc ^= a.x ^ a.y ^ a.z ^ a.w ^ c.x ^ c.y ^ c.z ^ c.w ^ (int)m;
    }
    asm volatile("" :: "v"(acc));   // keep loads live (rule #17), no store
    return;
  }

  // ---------------- DP wave (identical math to R7) ----------------
  const int l = threadIdx.x;
  const int al = act_lens[b];
  const int ll = label_lens[b];

  const int cll = ((ll & 1) << 6) | (ll >> 1);
  const int4 av = pA[(al + ll) * UP + cll];
  const float sg1 = lo16((uint32_t)av.x), sg2 = hi16((uint32_t)av.x);
  const float sg3 = lo16((uint32_t)av.y), sg4 = hi16((uint32_t)av.y);
  const int u0 = 2 * l, u1 = 2 * l + 1;
  const bool isLL0 = (u0 == ll), isLL1 = (u1 == ll);
  const int kbase = al + ll - 4;

  // history: h[0] = alpha(diag k-1), ..., h[4] = alpha(diag k-5); offsets o0/o1
  float h0[5] = {0, 0, 0, 0, 0}, h1[5] = {0, 0, 0, 0, 0};
  int o0 = 0, o1 = 0;
  if (l == 0) h0[0] = 1.0f;   // alpha(0,0) = 1 (diag 0); loop starts at k=1
  float tAm = 0.0f; int tAo = -100000;

  OpsP q[12];
#pragma unroll
  for (int j = 0; j < 12; ++j) q[j] = load_ops(pA, pM4, j + 1, l);

  for (int blk = 0; blk < 30; ++blk) {
    const int kblk = blk * 12 + 1;
#pragma unroll
    for (int w = 0; w < 3; ++w) {
      // ---- window start: renorm both slots, adopt dead offsets, scales ----
      float pv0 = fmaxf(fmaxf(fmaxf(h0[0], h0[1]), fmaxf(h0[2], h0[3])), h0[4]);
      int eb0 = (int)((__float_as_uint(pv0) >> 23) & 0xffu);
      bool dead0 = (eb0 == 0);
      int d0 = dead0 ? 0 : (127 - eb0);
#pragma unroll
      for (int i = 0; i < 5; ++i) h0[i] = ldexpf(h0[i], d0);
      o0 -= d0;
      float pv1 = fmaxf(fmaxf(fmaxf(h1[0], h1[1]), fmaxf(h1[2], h1[3])), h1[4]);
      int eb1 = (int)((__float_as_uint(pv1) >> 23) & 0xffu);
      bool dead1 = (eb1 == 0);
      int d1 = dead1 ? 0 : (127 - eb1);
#pragma unroll
      for (int i = 0; i < 5; ++i) h1[i] = ldexpf(h1[i], d1);
      o1 -= d1;
      // offset adoption for dead slots (3 rounds: outruns the diagonal front)
#pragma unroll
      for (int r = 0; r < 3; ++r) {
        int on = __shfl_up(o1, 1, 64);
        if (dead0 && l > 0) o0 = on;
        if (dead1) o1 = o0;
      }
      int on0 = __shfl_up(o1, 1, 64);
      float scN = (l == 0) ? 0.0f : mkscale(on0 - o0);  // help1(l-1) -> slot0
      float sc10 = mkscale(o0 - o1);                    // help0 -> slot1 (same lane)

      // ---- 4 diagonals, offsets frozen ----
#pragma unroll
      for (int j = 0; j < 4; ++j) {
        const int rj = w * 4 + j;
        const int k = kblk + rj;
        OpsP cur = q[rj];
        q[rj] = load_ops(pA, pM4, k + 12, l);   // row <= 372 < KP

        uint32_t a0x = (uint32_t)cur.a0.x, a0y = (uint32_t)cur.a0.y;
        uint32_t a0z = (uint32_t)cur.a0.z, a0w = (uint32_t)cur.a0.w;
        uint32_t a1x = (uint32_t)cur.a1.x, a1y = (uint32_t)cur.a1.y;
        uint32_t a1z = (uint32_t)cur.a1.z, a1w = (uint32_t)cur.a1.w;

        float self0 = fmaf(h0[0], lo16(a0x), fmaf(h0[1], hi16(a0x),
                       fmaf(h0[2], lo16(a0y), h0[3] * hi16(a0y))));
        float help0 = fmaf(h0[0], lo16(a0z), fmaf(h0[1], hi16(a0z),
                       fmaf(h0[2], lo16(a0w), fmaf(h0[3], hi16(a0w),
                        h0[4] * lo16(cur.m4)))));
        float self1 = fmaf(h1[0], lo16(a1x), fmaf(h1[1], hi16(a1x),
                       fmaf(h1[2], lo16(a1y), h1[3] * hi16(a1y))));
        float help1 = fmaf(h1[0], lo16(a1z), fmaf(h1[1], hi16(a1z),
                       fmaf(h1[2], lo16(a1w), fmaf(h1[3], hi16(a1w),
                        h1[4] * hi16(cur.m4)))));

        float n0 = __shfl_up(help1, 1, 64);     // mass into u0 from lane l-1
        float r0 = fmaf(n0, scN, self0);
        float r1 = fmaf(help0, sc10, self1);

        float r0g = ((unsigned)(k - u0) < (unsigned)T) ? r0 : 0.0f;
        float r1g = ((unsigned)(k - u1) < (unsigned)T) ? r1 : 0.0f;

        // final-term capture: alpha(al-d,ll) * S_d(al-d,ll) at k = al-d+ll
        unsigned idx = (unsigned)(k - kbase);
        if (idx < 4u) {
          if (isLL0 | isLL1) {
            float sg = (idx == 0) ? sg4 : (idx == 1) ? sg3 : (idx == 2) ? sg2 : sg1;
            float tm = (isLL0 ? r0g : r1g) * sg;
            int to = isLL0 ? o0 : o1;
            int nb2 = (tAo > to) ? tAo : to;
            tAm = ldexpf(tAm, tAo - nb2) + ldexpf(tm, to - nb2);
            tAo = nb2;
          }
        }

        // history shift: pure register renaming (offsets frozen in window)
        h0[4] = h0[3]; h0[3] = h0[2]; h0[2] = h0[1]; h0[1] = h0[0]; h0[0] = r0g;
        h1[4] = h1[3]; h1[3] = h1[2]; h1[2] = h1[1]; h1[1] = h1[0]; h1[0] = r1g;
      }
    }
  }

  if (isLL0 | isLL1) partial[b] = -(log2f(tAm) + (float)tAo) * LN2;
}

// ---------------- K3: batch reduce ----------------
__global__ void k_final(const float* __restrict__ partial, float* __restrict__ out) {
  if (threadIdx.x == 0 && blockIdx.x == 0)
    out[0] = (partial[0] + partial[1] + partial[2] + partial[3]) * 0.25f;
}

extern "C" void kernel_launch(void* const* d_in, const int* in_sizes, int n_in,
                              void* d_out, int out_size, void* d_ws, size_t ws_size,
                              hipStream_t stream) {
  const float* acts = (const float*)d_in[0];
  const int* labels = (const int*)d_in[1];
  const int* act_lens = (const int*)d_in[2];
  const int* label_lens = (const int*)d_in[3];
  float* ws = (float*)d_ws;
  __hip_bfloat16* A = (__hip_bfloat16*)ws;                 // CELLS x 8 bf16
  __hip_bfloat16* M4p = (__hip_bfloat16*)(ws + A_FLOATS);  // CELLS/2 x uint32
  float* partial = ws + A_FLOATS + M4_FLOATS;              // [B]
  float* out = (float*)d_out;

  int n4 = (A_FLOATS + M4_FLOATS) / 4;
  k_fill<<<(n4 + 255) / 256, 256, 0, stream>>>(reinterpret_cast<float4*>(ws), n4);
  k_prep<<<BTU / 4, 256, 0, stream>>>(acts, labels, A, M4p);
  k_dp<<<B, 192, 0, stream>>>(reinterpret_cast<const int4*>(A),
                              reinterpret_cast<const uint32_t*>(M4p),
                              act_lens, label_lens, partial);
  k_final<<<1, 64, 0, stream>>>(partial, out);
}